// Round 5
// baseline (247.958 us; speedup 1.0000x reference)
//
#include <hip/hip_runtime.h>

// Problem constants
#define NB      32      // batch
#define INF     128     // in_flt
#define NPIX    64      // N
#define TSP     16      // t
#define OUTF    32      // out_flt
#define FF      16      // intermediate features
#define D_IN    768     // 3*t*t
#define D_OUT   8192    // out_flt*t*t
#define NCOL    (D_OUT*FF)   // 131072
#define OUTCH   160     // in_flt + out_flt
#define BSTRIDE 655360  // 160*64*64 floats per batch in d_out
#define MOFF    524288  // 128*64*64: offset of out_a region per batch (M scratch)

// K1: fused strided conv (128ch,4x4,stride4 -> 3ch) + x->out concat copy.
// Writes A TRANSPOSED as At2[bg][k][4]: At2[(b>>2)*3072 + k*4 + (b&3)],
// so each K2 wave (bg) streams its A contiguously at uniform addresses.
__global__ __launch_bounds__(256) void k1_conv_copy(
    const float* __restrict__ x, const float* __restrict__ wc,
    float* __restrict__ out, float* __restrict__ At2)
{
    __shared__ float sW[3*128*16];     // w_conv, 24 KB
    __shared__ float sP[16][16][3];    // partials [icg][j][c3]
    const int b   = blockIdx.x >> 4;
    const int oi  = blockIdx.x & 15;
    const int tid = threadIdx.x;
    for (int idx = tid; idx < 6144; idx += 256) sW[idx] = wc[idx];
    __syncthreads();
    const int icg = tid >> 4;          // 0..15 -> ic block of 8
    const int j   = tid & 15;          // output col
    float a0 = 0.f, a1 = 0.f, a2 = 0.f;
    for (int ic8 = 0; ic8 < 8; ++ic8) {
        const int ic = icg*8 + ic8;
        #pragma unroll
        for (int ki = 0; ki < 4; ++ki) {
            const int row = 4*oi + ki;
            const float4 xv = *(const float4*)(x + ((size_t)(b*INF+ic)*NPIX + row)*NPIX + 4*j);
            *(float4*)(out + ((size_t)(b*OUTCH+ic)*NPIX + row)*NPIX + 4*j) = xv;
            const float* w0 = sW + ((0*INF+ic)*4 + ki)*4;
            const float* w1 = sW + ((1*INF+ic)*4 + ki)*4;
            const float* w2 = sW + ((2*INF+ic)*4 + ki)*4;
            a0 += xv.x*w0[0] + xv.y*w0[1] + xv.z*w0[2] + xv.w*w0[3];
            a1 += xv.x*w1[0] + xv.y*w1[1] + xv.z*w1[2] + xv.w*w1[3];
            a2 += xv.x*w2[0] + xv.y*w2[1] + xv.z*w2[2] + xv.w*w2[3];
        }
    }
    sP[icg][j][0] = a0; sP[icg][j][1] = a1; sP[icg][j][2] = a2;
    __syncthreads();
    if (tid < 48) {
        const int c3 = tid >> 4, jj = tid & 15;
        float s = 0.f;
        #pragma unroll
        for (int g = 0; g < 16; ++g) s += sP[g][jj][c3];
        const int k = c3*256 + oi*16 + jj;    // reshape(3,16,16) C-order
        At2[(b >> 2)*3072 + k*4 + (b & 3)] = s;
    }
}

// K2: M[b, col] = sum_k A[k][b] * T[k, col], register-tiled 4b x 4col.
// ZERO LDS (R0-R3 all capped at 8 waves/CU ~ 8 KB in flight < 9.2 KB
// latency-BW product -> latency-bound). Now: 2 blocks/CU = 16 waves/CU,
// 8 named-register T loads in flight per wave, 1:1 fmac<->load interleave
// (AITER pattern). A read at wave-uniform addresses from At2 (scalar/L2
// path, lgkmcnt if scalarized - independent of the T vmcnt queue).
// __launch_bounds__(512,4): allocator targets 4 waves/EU, VGPR cap 128,
// so it does NOT crush the ring to depth-1 like R3 (VGPR_Count=32).
__global__ __launch_bounds__(512, 4) void k2_gemm(
    const float* __restrict__ At2, const float* __restrict__ Tm,
    float* __restrict__ out)
{
    const int tid  = threadIdx.x;
    const int cg   = tid & 63;                                   // 64 col-groups
    const int bg   = __builtin_amdgcn_readfirstlane(tid >> 6);   // wave-uniform b-group
    const int col4 = blockIdx.x*256 + cg*4;

    float acc[4][4];
    #pragma unroll
    for (int i = 0; i < 4; ++i)
        #pragma unroll
        for (int j = 0; j < 4; ++j) acc[i][j] = 0.f;

    const float*  tp = Tm + col4;
    const float4* ap = (const float4*)(At2 + (size_t)bg*3072);   // uniform stream

#define TLD(KK) (*(const float4*)(tp + (size_t)(KK)*NCOL))
#define FM(T4, A4) { \
    acc[0][0]+=A4.x*T4.x; acc[0][1]+=A4.x*T4.y; acc[0][2]+=A4.x*T4.z; acc[0][3]+=A4.x*T4.w; \
    acc[1][0]+=A4.y*T4.x; acc[1][1]+=A4.y*T4.y; acc[1][2]+=A4.y*T4.z; acc[1][3]+=A4.y*T4.w; \
    acc[2][0]+=A4.z*T4.x; acc[2][1]+=A4.z*T4.y; acc[2][2]+=A4.z*T4.z; acc[2][3]+=A4.z*T4.w; \
    acc[3][0]+=A4.w*T4.x; acc[3][1]+=A4.w*T4.y; acc[3][2]+=A4.w*T4.z; acc[3][3]+=A4.w*T4.w; }

    float4 t0=TLD(0), t1=TLD(1), t2=TLD(2), t3=TLD(3),
           t4=TLD(4), t5=TLD(5), t6=TLD(6), t7=TLD(7);

    int k0 = 0;
    for (; k0 < D_IN - 8; k0 += 8) {
        const float4 a0 = ap[k0+0], a1 = ap[k0+1], a2 = ap[k0+2], a3 = ap[k0+3];
        const float4 a4 = ap[k0+4], a5 = ap[k0+5], a6 = ap[k0+6], a7 = ap[k0+7];
        FM(t0, a0); t0 = TLD(k0+8);
        FM(t1, a1); t1 = TLD(k0+9);
        FM(t2, a2); t2 = TLD(k0+10);
        FM(t3, a3); t3 = TLD(k0+11);
        FM(t4, a4); t4 = TLD(k0+12);
        FM(t5, a5); t5 = TLD(k0+13);
        FM(t6, a6); t6 = TLD(k0+14);
        FM(t7, a7); t7 = TLD(k0+15);
    }
    {   // epilogue: k0 == D_IN-8, consume only
        const float4 a0 = ap[k0+0], a1 = ap[k0+1], a2 = ap[k0+2], a3 = ap[k0+3];
        const float4 a4 = ap[k0+4], a5 = ap[k0+5], a6 = ap[k0+6], a7 = ap[k0+7];
        FM(t0, a0); FM(t1, a1); FM(t2, a2); FM(t3, a3);
        FM(t4, a4); FM(t5, a5); FM(t6, a6); FM(t7, a7);
    }
#undef FM
#undef TLD

    #pragma unroll
    for (int bb = 0; bb < 4; ++bb)
        *(float4*)(out + (size_t)(bg*4 + bb)*BSTRIDE + MOFF + col4) =
            make_float4(acc[bb][0], acc[bb][1], acc[bb][2], acc[bb][3]);
}

// K3: out[j,d] = sum_i exp(-sum_f |M[i,d,f]-M[j,d,f]|) - 1.
__global__ __launch_bounds__(256) void k3_pairs(
    const float* __restrict__ outM,    // d_out base (M lives in out_a slots)
    float* __restrict__ outS)
{
    extern __shared__ float sM[];      // 32*32*17 floats
    const int tid = threadIdx.x;
    const int dd0 = blockIdx.x * 32;
    for (int idx = tid; idx < 32*32*16; idx += 256) {
        const int i = idx >> 9, rem = idx & 511, d = rem >> 4, f = rem & 15;
        sM[(i*32 + d)*17 + f] =
            outM[(size_t)i*BSTRIDE + MOFF + (size_t)(dd0 + d)*16 + f];
    }
    __syncthreads();
    const int j = tid >> 3;
    for (int q = 0; q < 4; ++q) {
        const int d = (tid & 7) + q*8;
        float mj[16];
        const float* pj = sM + (j*32 + d)*17;
        #pragma unroll
        for (int f = 0; f < 16; ++f) mj[f] = pj[f];
        float acc = 0.f;
        for (int i = 0; i < 32; ++i) {
            const float* pi = sM + (i*32 + d)*17;
            float dist = 0.f;
            #pragma unroll
            for (int f = 0; f < 16; ++f) dist += fabsf(pi[f] - mj[f]);
            acc += __expf(-dist);
        }
        outS[(size_t)j*D_OUT + dd0 + d] = acc - 1.0f;
    }
}

// K4: ConvTranspose2d, stride==kernel -> no overlap.
__global__ __launch_bounds__(256) void k4_deconv(
    const float* __restrict__ outS, const float* __restrict__ wd,
    float* __restrict__ out)
{
    __shared__ float sO[32*256];       // [ic][si*16+sj]
    __shared__ float sWd[32*16];       // [ic][ki*4+kj]
    const int b   = blockIdx.x >> 5;
    const int oc  = blockIdx.x & 31;
    const int tid = threadIdx.x;
    for (int idx = tid; idx < 8192; idx += 256) sO[idx] = outS[(size_t)b*D_OUT + idx];
    for (int idx = tid; idx < 512; idx += 256) {
        const int ic = idx >> 4, r = idx & 15;
        sWd[idx] = wd[((ic*32 + oc) << 4) + r];   // IOHW: (ic, oc, ki, kj)
    }
    __syncthreads();
    float* ob = out + (size_t)b*BSTRIDE + (size_t)(128 + oc)*4096;
    for (int s = 0; s < 16; ++s) {
        const int p  = tid + (s << 8);
        const int i  = p >> 6, jc = p & 63;
        const int si = i >> 2, ki = i & 3, sj = jc >> 2, kj = jc & 3;
        float acc = 0.f;
        #pragma unroll
        for (int ic = 0; ic < 32; ++ic)
            acc += sO[ic*256 + si*16 + sj] * sWd[ic*16 + ki*4 + kj];
        ob[p] = acc;
    }
}

extern "C" void kernel_launch(void* const* d_in, const int* in_sizes, int n_in,
                              void* d_out, int out_size, void* d_ws, size_t ws_size,
                              hipStream_t stream) {
    const float* x  = (const float*)d_in[0];
    const float* wc = (const float*)d_in[1];
    const float* Tm = (const float*)d_in[2];
    const float* wd = (const float*)d_in[3];
    float* out  = (float*)d_out;
    float* At2  = (float*)d_ws;                        // 8*768*4 floats = 96 KB
    float* outS = (float*)((char*)d_ws + (1 << 17));   // 1 MB at +128 KB

    k1_conv_copy<<<NB*TSP, 256, 0, stream>>>(x, wc, out, At2);                  // 512 blocks
    k2_gemm    <<<NCOL/256, 512, 0, stream>>>(At2, Tm, out);                    // 512 blocks
    k3_pairs   <<<D_OUT/32, 256, 32*32*17*sizeof(float), stream>>>(out, outS);  // 256 blocks
    k4_deconv  <<<NB*OUTF, 256, 0, stream>>>(outS, wd, out);                    // 1024 blocks
}

// Round 6
// 186.753 us; speedup vs baseline: 1.3277x; 1.3277x over previous
//
#include <hip/hip_runtime.h>

// Problem constants
#define NB      32      // batch
#define INF     128     // in_flt
#define NPIX    64      // N
#define TSP     16      // t
#define OUTF    32      // out_flt
#define FF      16      // intermediate features
#define D_IN    768     // 3*t*t
#define D_OUT   8192    // out_flt*t*t
#define NCOL    (D_OUT*FF)   // 131072
#define OUTCH   160     // in_flt + out_flt
#define BSTRIDE 655360  // 160*64*64 floats per batch in d_out
#define MOFF    524288  // 128*64*64: offset of out_a region per batch (M scratch)

// K1: fused strided conv (128ch,4x4,stride4 -> 3ch) + x->out concat copy.
// A written k-major: At[k*32 + b].
__global__ __launch_bounds__(256) void k1_conv_copy(
    const float* __restrict__ x, const float* __restrict__ wc,
    float* __restrict__ out, float* __restrict__ At)
{
    __shared__ float sW[3*128*16];     // w_conv, 24 KB
    __shared__ float sP[16][16][3];    // partials [icg][j][c3]
    const int b   = blockIdx.x >> 4;
    const int oi  = blockIdx.x & 15;
    const int tid = threadIdx.x;
    for (int idx = tid; idx < 6144; idx += 256) sW[idx] = wc[idx];
    __syncthreads();
    const int icg = tid >> 4;          // 0..15 -> ic block of 8
    const int j   = tid & 15;          // output col
    float a0 = 0.f, a1 = 0.f, a2 = 0.f;
    for (int ic8 = 0; ic8 < 8; ++ic8) {
        const int ic = icg*8 + ic8;
        #pragma unroll
        for (int ki = 0; ki < 4; ++ki) {
            const int row = 4*oi + ki;
            const float4 xv = *(const float4*)(x + ((size_t)(b*INF+ic)*NPIX + row)*NPIX + 4*j);
            *(float4*)(out + ((size_t)(b*OUTCH+ic)*NPIX + row)*NPIX + 4*j) = xv;
            const float* w0 = sW + ((0*INF+ic)*4 + ki)*4;
            const float* w1 = sW + ((1*INF+ic)*4 + ki)*4;
            const float* w2 = sW + ((2*INF+ic)*4 + ki)*4;
            a0 += xv.x*w0[0] + xv.y*w0[1] + xv.z*w0[2] + xv.w*w0[3];
            a1 += xv.x*w1[0] + xv.y*w1[1] + xv.z*w1[2] + xv.w*w1[3];
            a2 += xv.x*w2[0] + xv.y*w2[1] + xv.z*w2[2] + xv.w*w2[3];
        }
    }
    sP[icg][j][0] = a0; sP[icg][j][1] = a1; sP[icg][j][2] = a2;
    __syncthreads();
    if (tid < 48) {
        const int c3 = tid >> 4, jj = tid & 15;
        float s = 0.f;
        #pragma unroll
        for (int g = 0; g < 16; ++g) s += sP[g][jj][c3];
        const int k = c3*256 + oi*16 + jj;    // reshape(3,16,16) C-order
        At[k*32 + b] = s;
    }
}

// K2 v6: M[b,col] = sum_k A[k][b] * T[k,col].
// Design rationale (R0-R5 post-mortems):
//  - Each WAVE owns a unique 256-col range (zero T redundancy: no reliance
//    on L1/L2 for correctness of the fetch volume). Batches split across
//    waves: wave = (colRange in {0,1}) x (bg in {0..3}); lane = 4col x 8b.
//  - A via LDS broadcast (lgkmcnt) so the vmcnt queue holds ONLY the T-ring
//    (R4's ring was drained every iter by A-loads sharing the in-order
//    vmcnt queue). 8 named-reg T loads in flight = 8KB/wave, 64KB/CU.
//  - 256 blocks x 512thr = exactly 1 block/CU; launch_bounds(512,2) caps
//    allocator pressure at VGPR<=256 so the ring isn't collapsed (R3: 32).
__global__ __launch_bounds__(512, 2) void k2_gemm(
    const float* __restrict__ At, const float* __restrict__ Tm,
    float* __restrict__ out)
{
    extern __shared__ float sA[];      // D_IN*32 = 24576 floats = 96 KB
    const int tid = threadIdx.x;
    {   // stage all of At, coalesced float4
        const float4* src = (const float4*)At;
        float4* dst = (float4*)sA;
        #pragma unroll
        for (int i = 0; i < 12; ++i)
            dst[tid + i*512] = src[tid + i*512];
    }
    __syncthreads();
    const int w    = tid >> 6;                 // wave 0..7
    const int lane = tid & 63;
    const int bg   = w >> 1;                   // batch-group of 8 (wave-uniform)
    const int col4 = blockIdx.x*512 + (w & 1)*256 + lane*4;  // unique per lane

    float acc[8][4];
    #pragma unroll
    for (int i = 0; i < 8; ++i)
        #pragma unroll
        for (int j = 0; j < 4; ++j) acc[i][j] = 0.f;

    const float* tp    = Tm + col4;
    const float* aBase = sA + bg*8;            // wave-uniform -> ds broadcast

#define TLD(KK) (*(const float4*)(tp + (size_t)(KK)*NCOL))
#define FM32(T4, AL, AH) { \
  acc[0][0]+=AL.x*T4.x; acc[0][1]+=AL.x*T4.y; acc[0][2]+=AL.x*T4.z; acc[0][3]+=AL.x*T4.w; \
  acc[1][0]+=AL.y*T4.x; acc[1][1]+=AL.y*T4.y; acc[1][2]+=AL.y*T4.z; acc[1][3]+=AL.y*T4.w; \
  acc[2][0]+=AL.z*T4.x; acc[2][1]+=AL.z*T4.y; acc[2][2]+=AL.z*T4.z; acc[2][3]+=AL.z*T4.w; \
  acc[3][0]+=AL.w*T4.x; acc[3][1]+=AL.w*T4.y; acc[3][2]+=AL.w*T4.z; acc[3][3]+=AL.w*T4.w; \
  acc[4][0]+=AH.x*T4.x; acc[4][1]+=AH.x*T4.y; acc[4][2]+=AH.x*T4.z; acc[4][3]+=AH.x*T4.w; \
  acc[5][0]+=AH.y*T4.x; acc[5][1]+=AH.y*T4.y; acc[5][2]+=AH.y*T4.z; acc[5][3]+=AH.y*T4.w; \
  acc[6][0]+=AH.z*T4.x; acc[6][1]+=AH.z*T4.y; acc[6][2]+=AH.z*T4.z; acc[6][3]+=AH.z*T4.w; \
  acc[7][0]+=AH.w*T4.x; acc[7][1]+=AH.w*T4.y; acc[7][2]+=AH.w*T4.z; acc[7][3]+=AH.w*T4.w; }
#define STEP(J, TT) { \
    const float4 aL = *(const float4*)(aBase + (k0+(J))*32); \
    const float4 aH = *(const float4*)(aBase + (k0+(J))*32 + 4); \
    FM32(TT, aL, aH); TT = TLD(k0 + 8 + (J)); }
#define STEPE(J, TT) { \
    const float4 aL = *(const float4*)(aBase + (k0+(J))*32); \
    const float4 aH = *(const float4*)(aBase + (k0+(J))*32 + 4); \
    FM32(TT, aL, aH); }

    float4 t0=TLD(0), t1=TLD(1), t2=TLD(2), t3=TLD(3),
           t4=TLD(4), t5=TLD(5), t6=TLD(6), t7=TLD(7);

    int k0 = 0;
    for (; k0 < D_IN - 8; k0 += 8) {
        STEP(0, t0) STEP(1, t1) STEP(2, t2) STEP(3, t3)
        STEP(4, t4) STEP(5, t5) STEP(6, t6) STEP(7, t7)
    }
    // epilogue: k0 == D_IN-8, consume only
    STEPE(0, t0) STEPE(1, t1) STEPE(2, t2) STEPE(3, t3)
    STEPE(4, t4) STEPE(5, t5) STEPE(6, t6) STEPE(7, t7)
#undef STEPE
#undef STEP
#undef FM32
#undef TLD

    #pragma unroll
    for (int bb = 0; bb < 8; ++bb)
        *(float4*)(out + (size_t)(bg*8 + bb)*BSTRIDE + MOFF + col4) =
            make_float4(acc[bb][0], acc[bb][1], acc[bb][2], acc[bb][3]);
}

// K3: out[j,d] = sum_i exp(-sum_f |M[i,d,f]-M[j,d,f]|) - 1.
__global__ __launch_bounds__(256) void k3_pairs(
    const float* __restrict__ outM,    // d_out base (M lives in out_a slots)
    float* __restrict__ outS)
{
    extern __shared__ float sM[];      // 32*32*17 floats
    const int tid = threadIdx.x;
    const int dd0 = blockIdx.x * 32;
    for (int idx = tid; idx < 32*32*16; idx += 256) {
        const int i = idx >> 9, rem = idx & 511, d = rem >> 4, f = rem & 15;
        sM[(i*32 + d)*17 + f] =
            outM[(size_t)i*BSTRIDE + MOFF + (size_t)(dd0 + d)*16 + f];
    }
    __syncthreads();
    const int j = tid >> 3;
    for (int q = 0; q < 4; ++q) {
        const int d = (tid & 7) + q*8;
        float mj[16];
        const float* pj = sM + (j*32 + d)*17;
        #pragma unroll
        for (int f = 0; f < 16; ++f) mj[f] = pj[f];
        float acc = 0.f;
        for (int i = 0; i < 32; ++i) {
            const float* pi = sM + (i*32 + d)*17;
            float dist = 0.f;
            #pragma unroll
            for (int f = 0; f < 16; ++f) dist += fabsf(pi[f] - mj[f]);
            acc += __expf(-dist);
        }
        outS[(size_t)j*D_OUT + dd0 + d] = acc - 1.0f;
    }
}

// K4: ConvTranspose2d, stride==kernel -> no overlap.
__global__ __launch_bounds__(256) void k4_deconv(
    const float* __restrict__ outS, const float* __restrict__ wd,
    float* __restrict__ out)
{
    __shared__ float sO[32*256];       // [ic][si*16+sj]
    __shared__ float sWd[32*16];       // [ic][ki*4+kj]
    const int b   = blockIdx.x >> 5;
    const int oc  = blockIdx.x & 31;
    const int tid = threadIdx.x;
    for (int idx = tid; idx < 8192; idx += 256) sO[idx] = outS[(size_t)b*D_OUT + idx];
    for (int idx = tid; idx < 512; idx += 256) {
        const int ic = idx >> 4, r = idx & 15;
        sWd[idx] = wd[((ic*32 + oc) << 4) + r];   // IOHW: (ic, oc, ki, kj)
    }
    __syncthreads();
    float* ob = out + (size_t)b*BSTRIDE + (size_t)(128 + oc)*4096;
    for (int s = 0; s < 16; ++s) {
        const int p  = tid + (s << 8);
        const int i  = p >> 6, jc = p & 63;
        const int si = i >> 2, ki = i & 3, sj = jc >> 2, kj = jc & 3;
        float acc = 0.f;
        #pragma unroll
        for (int ic = 0; ic < 32; ++ic)
            acc += sO[ic*256 + si*16 + sj] * sWd[ic*16 + ki*4 + kj];
        ob[p] = acc;
    }
}

extern "C" void kernel_launch(void* const* d_in, const int* in_sizes, int n_in,
                              void* d_out, int out_size, void* d_ws, size_t ws_size,
                              hipStream_t stream) {
    const float* x  = (const float*)d_in[0];
    const float* wc = (const float*)d_in[1];
    const float* Tm = (const float*)d_in[2];
    const float* wd = (const float*)d_in[3];
    float* out  = (float*)d_out;
    float* At   = (float*)d_ws;                        // 98304 B
    float* outS = (float*)((char*)d_ws + (1 << 17));   // 1 MB at +128 KB

    k1_conv_copy<<<NB*TSP, 256, 0, stream>>>(x, wc, out, At);                   // 512 blocks
    k2_gemm    <<<NCOL/512, 512, D_IN*32*sizeof(float), stream>>>(At, Tm, out); // 256 blocks
    k3_pairs   <<<D_OUT/32, 256, 32*32*17*sizeof(float), stream>>>(out, outS);  // 256 blocks
    k4_deconv  <<<NB*OUTF, 256, 0, stream>>>(outS, wd, out);                    // 1024 blocks
}

// Round 7
// 184.361 us; speedup vs baseline: 1.3450x; 1.0130x over previous
//
#include <hip/hip_runtime.h>

// Problem constants
#define NB      32      // batch
#define INF     128     // in_flt
#define NPIX    64      // N
#define TSP     16      // t
#define OUTF    32      // out_flt
#define FF      16      // intermediate features
#define D_IN    768     // 3*t*t
#define D_OUT   8192    // out_flt*t*t
#define NCOL    (D_OUT*FF)   // 131072
#define OUTCH   160     // in_flt + out_flt
#define BSTRIDE 655360  // 160*64*64 floats per batch in d_out
#define MOFF    524288  // 128*64*64: offset of out_a region per batch (M scratch)

// K1: fused strided conv (128ch,4x4,stride4 -> 3ch) + x->out concat copy.
// A written k-major: At[k*32 + b].
__global__ __launch_bounds__(256) void k1_conv_copy(
    const float* __restrict__ x, const float* __restrict__ wc,
    float* __restrict__ out, float* __restrict__ At)
{
    __shared__ float sW[3*128*16];     // w_conv, 24 KB
    __shared__ float sP[16][16][3];    // partials [icg][j][c3]
    const int b   = blockIdx.x >> 4;
    const int oi  = blockIdx.x & 15;
    const int tid = threadIdx.x;
    for (int idx = tid; idx < 6144; idx += 256) sW[idx] = wc[idx];
    __syncthreads();
    const int icg = tid >> 4;          // 0..15 -> ic block of 8
    const int j   = tid & 15;          // output col
    float a0 = 0.f, a1 = 0.f, a2 = 0.f;
    for (int ic8 = 0; ic8 < 8; ++ic8) {
        const int ic = icg*8 + ic8;
        #pragma unroll
        for (int ki = 0; ki < 4; ++ki) {
            const int row = 4*oi + ki;
            const float4 xv = *(const float4*)(x + ((size_t)(b*INF+ic)*NPIX + row)*NPIX + 4*j);
            *(float4*)(out + ((size_t)(b*OUTCH+ic)*NPIX + row)*NPIX + 4*j) = xv;
            const float* w0 = sW + ((0*INF+ic)*4 + ki)*4;
            const float* w1 = sW + ((1*INF+ic)*4 + ki)*4;
            const float* w2 = sW + ((2*INF+ic)*4 + ki)*4;
            a0 += xv.x*w0[0] + xv.y*w0[1] + xv.z*w0[2] + xv.w*w0[3];
            a1 += xv.x*w1[0] + xv.y*w1[1] + xv.z*w1[2] + xv.w*w1[3];
            a2 += xv.x*w2[0] + xv.y*w2[1] + xv.z*w2[2] + xv.w*w2[3];
        }
    }
    sP[icg][j][0] = a0; sP[icg][j][1] = a1; sP[icg][j][2] = a2;
    __syncthreads();
    if (tid < 48) {
        const int c3 = tid >> 4, jj = tid & 15;
        float s = 0.f;
        #pragma unroll
        for (int g = 0; g < 16; ++g) s += sP[g][jj][c3];
        const int k = c3*256 + oi*16 + jj;    // reshape(3,16,16) C-order
        At[k*32 + b] = s;
    }
}

// K2 v7: M[b,col] = sum_k A[k][b] * T[k,col].
// R6 post-mortem: ~485 cyc/k vs 128 VALU -> ds_read latency (~120cy x2) was
// on the critical path (FM consumed A loaded in the SAME step; 2 waves/SIMD
// can't hide it). v7 software-pipelines A by ONE k-step: issue k+1's
// ds_reads, then k's 32 fmacs (128 issue-cyc >= 120cy LDS latency) -> hidden.
// sA has a pad row at k=768 so the epilogue's dead prefetch needs no guard.
// Keeps: unique-col waves (zero T redundancy), 8-deep named-reg T-ring on a
// PURE vmcnt queue, launch_bounds(512,2), 256 blocks = 1 block/CU.
__global__ __launch_bounds__(512, 2) void k2_gemm(
    const float* __restrict__ At, const float* __restrict__ Tm,
    float* __restrict__ out)
{
    extern __shared__ float sA[];      // (D_IN+1)*32 floats = 96 KB + 128 B
    const int tid = threadIdx.x;
    {   // stage all of At, coalesced float4
        const float4* src = (const float4*)At;
        float4* dst = (float4*)sA;
        #pragma unroll
        for (int i = 0; i < 12; ++i)
            dst[tid + i*512] = src[tid + i*512];
    }
    __syncthreads();
    const int w    = tid >> 6;                 // wave 0..7
    const int lane = tid & 63;
    const int bg   = w >> 1;                   // batch-group of 8 (wave-uniform)
    const int col4 = blockIdx.x*512 + (w & 1)*256 + lane*4;  // unique per lane

    float acc[8][4];
    #pragma unroll
    for (int i = 0; i < 8; ++i)
        #pragma unroll
        for (int j = 0; j < 4; ++j) acc[i][j] = 0.f;

    const float* tp    = Tm + col4;
    const float* aBase = sA + bg*8;            // wave-uniform -> ds broadcast

#define TLD(KK) (*(const float4*)(tp + (size_t)(KK)*NCOL))
#define FM32(T4, AL, AH) { \
  acc[0][0]+=AL.x*T4.x; acc[0][1]+=AL.x*T4.y; acc[0][2]+=AL.x*T4.z; acc[0][3]+=AL.x*T4.w; \
  acc[1][0]+=AL.y*T4.x; acc[1][1]+=AL.y*T4.y; acc[1][2]+=AL.y*T4.z; acc[1][3]+=AL.y*T4.w; \
  acc[2][0]+=AL.z*T4.x; acc[2][1]+=AL.z*T4.y; acc[2][2]+=AL.z*T4.z; acc[2][3]+=AL.z*T4.w; \
  acc[3][0]+=AL.w*T4.x; acc[3][1]+=AL.w*T4.y; acc[3][2]+=AL.w*T4.z; acc[3][3]+=AL.w*T4.w; \
  acc[4][0]+=AH.x*T4.x; acc[4][1]+=AH.x*T4.y; acc[4][2]+=AH.x*T4.z; acc[4][3]+=AH.x*T4.w; \
  acc[5][0]+=AH.y*T4.x; acc[5][1]+=AH.y*T4.y; acc[5][2]+=AH.y*T4.z; acc[5][3]+=AH.y*T4.w; \
  acc[6][0]+=AH.z*T4.x; acc[6][1]+=AH.z*T4.y; acc[6][2]+=AH.z*T4.z; acc[6][3]+=AH.z*T4.w; \
  acc[7][0]+=AH.w*T4.x; acc[7][1]+=AH.w*T4.y; acc[7][2]+=AH.w*T4.z; acc[7][3]+=AH.w*T4.w; }
// STEP: issue next-k A ds_reads FIRST, then FM on current A (loaded last
// step; its lgkmcnt wait is behind 32 fmacs + 1 global-load of issue),
// then reload the T-ring slot and rotate A.
#define STEP(J, TT) { \
    const float4 naL = *(const float4*)(aBase + (k0+(J)+1)*32); \
    const float4 naH = *(const float4*)(aBase + (k0+(J)+1)*32 + 4); \
    FM32(TT, aL, aH); TT = TLD(k0 + 8 + (J)); \
    aL = naL; aH = naH; }
#define STEPE(J, TT) { \
    const float4 naL = *(const float4*)(aBase + (k0+(J)+1)*32); \
    const float4 naH = *(const float4*)(aBase + (k0+(J)+1)*32 + 4); \
    FM32(TT, aL, aH); \
    aL = naL; aH = naH; }

    float4 t0=TLD(0), t1=TLD(1), t2=TLD(2), t3=TLD(3),
           t4=TLD(4), t5=TLD(5), t6=TLD(6), t7=TLD(7);
    float4 aL = *(const float4*)(aBase);       // k=0 row
    float4 aH = *(const float4*)(aBase + 4);

    int k0 = 0;
    for (; k0 < D_IN - 8; k0 += 8) {
        STEP(0, t0) STEP(1, t1) STEP(2, t2) STEP(3, t3)
        STEP(4, t4) STEP(5, t5) STEP(6, t6) STEP(7, t7)
    }
    // epilogue: k0 == D_IN-8, consume only (last prefetch hits the pad row)
    STEPE(0, t0) STEPE(1, t1) STEPE(2, t2) STEPE(3, t3)
    STEPE(4, t4) STEPE(5, t5) STEPE(6, t6) STEPE(7, t7)
#undef STEPE
#undef STEP
#undef FM32
#undef TLD

    #pragma unroll
    for (int bb = 0; bb < 8; ++bb)
        *(float4*)(out + (size_t)(bg*8 + bb)*BSTRIDE + MOFF + col4) =
            make_float4(acc[bb][0], acc[bb][1], acc[bb][2], acc[bb][3]);
}

// K3: out[j,d] = sum_i exp(-sum_f |M[i,d,f]-M[j,d,f]|) - 1.
__global__ __launch_bounds__(256) void k3_pairs(
    const float* __restrict__ outM,    // d_out base (M lives in out_a slots)
    float* __restrict__ outS)
{
    extern __shared__ float sM[];      // 32*32*17 floats
    const int tid = threadIdx.x;
    const int dd0 = blockIdx.x * 32;
    for (int idx = tid; idx < 32*32*16; idx += 256) {
        const int i = idx >> 9, rem = idx & 511, d = rem >> 4, f = rem & 15;
        sM[(i*32 + d)*17 + f] =
            outM[(size_t)i*BSTRIDE + MOFF + (size_t)(dd0 + d)*16 + f];
    }
    __syncthreads();
    const int j = tid >> 3;
    for (int q = 0; q < 4; ++q) {
        const int d = (tid & 7) + q*8;
        float mj[16];
        const float* pj = sM + (j*32 + d)*17;
        #pragma unroll
        for (int f = 0; f < 16; ++f) mj[f] = pj[f];
        float acc = 0.f;
        for (int i = 0; i < 32; ++i) {
            const float* pi = sM + (i*32 + d)*17;
            float dist = 0.f;
            #pragma unroll
            for (int f = 0; f < 16; ++f) dist += fabsf(pi[f] - mj[f]);
            acc += __expf(-dist);
        }
        outS[(size_t)j*D_OUT + dd0 + d] = acc - 1.0f;
    }
}

// K4: ConvTranspose2d, stride==kernel -> no overlap.
__global__ __launch_bounds__(256) void k4_deconv(
    const float* __restrict__ outS, const float* __restrict__ wd,
    float* __restrict__ out)
{
    __shared__ float sO[32*256];       // [ic][si*16+sj]
    __shared__ float sWd[32*16];       // [ic][ki*4+kj]
    const int b   = blockIdx.x >> 5;
    const int oc  = blockIdx.x & 31;
    const int tid = threadIdx.x;
    for (int idx = tid; idx < 8192; idx += 256) sO[idx] = outS[(size_t)b*D_OUT + idx];
    for (int idx = tid; idx < 512; idx += 256) {
        const int ic = idx >> 4, r = idx & 15;
        sWd[idx] = wd[((ic*32 + oc) << 4) + r];   // IOHW: (ic, oc, ki, kj)
    }
    __syncthreads();
    float* ob = out + (size_t)b*BSTRIDE + (size_t)(128 + oc)*4096;
    for (int s = 0; s < 16; ++s) {
        const int p  = tid + (s << 8);
        const int i  = p >> 6, jc = p & 63;
        const int si = i >> 2, ki = i & 3, sj = jc >> 2, kj = jc & 3;
        float acc = 0.f;
        #pragma unroll
        for (int ic = 0; ic < 32; ++ic)
            acc += sO[ic*256 + si*16 + sj] * sWd[ic*16 + ki*4 + kj];
        ob[p] = acc;
    }
}

extern "C" void kernel_launch(void* const* d_in, const int* in_sizes, int n_in,
                              void* d_out, int out_size, void* d_ws, size_t ws_size,
                              hipStream_t stream) {
    const float* x  = (const float*)d_in[0];
    const float* wc = (const float*)d_in[1];
    const float* Tm = (const float*)d_in[2];
    const float* wd = (const float*)d_in[3];
    float* out  = (float*)d_out;
    float* At   = (float*)d_ws;                        // 98304 B
    float* outS = (float*)((char*)d_ws + (1 << 17));   // 1 MB at +128 KB

    k1_conv_copy<<<NB*TSP, 256, 0, stream>>>(x, wc, out, At);                   // 512 blocks
    k2_gemm    <<<NCOL/512, 512, (D_IN+1)*32*sizeof(float), stream>>>(At, Tm, out); // 256 blocks
    k3_pairs   <<<D_OUT/32, 256, 32*32*17*sizeof(float), stream>>>(out, outS);  // 256 blocks
    k4_deconv  <<<NB*OUTF, 256, 0, stream>>>(outS, wd, out);                    // 1024 blocks
}